// Round 4
// baseline (378.029 us; speedup 1.0000x reference)
//
#include <hip/hip_runtime.h>

// Problem constants (n_steps==64 fixed for this instance).
#define BDIM 4096
#define DX 512
#define DZ 512
#define DY 256
#define HD 2048
#define NSTEPS 64

typedef __attribute__((ext_vector_type(8))) short bf16x8;   // 8 bf16 = 4 VGPRs
typedef __attribute__((ext_vector_type(4))) float f32x4;

__device__ inline unsigned short f2bf(float f) {  // RNE f32 -> bf16
    unsigned u = __float_as_uint(f);
    unsigned r = 0x7FFFu + ((u >> 16) & 1u);
    return (unsigned short)((u + r) >> 16);
}
__device__ inline float bf2f(unsigned short h) {
    return __uint_as_float(((unsigned)h) << 16);
}

// async global->LDS, 16B per lane (used ONLY in the twice-proven gemm_bf16)
#define GLDS16(g, l)                                                            \
    __builtin_amdgcn_global_load_lds((const __attribute__((address_space(1))) void*)(g), \
                                     (__attribute__((address_space(3))) void*)(l), 16, 0, 0)

// ---------------------------------------------------------------------------
// Batched f32 -> bf16 convert; lo-part optional (hi/lo split decomposition).
struct CvtJobs {
    const float* src[6];
    unsigned short* hi[6];
    unsigned short* lo[6];   // null -> hi only
    int n4[6];               // element count / 4
};
__global__ __launch_bounds__(256) void cvt_multi_k(CvtJobs J) {
    const int j = blockIdx.y;
    const int i4 = blockIdx.x * 256 + threadIdx.x;
    if (i4 >= J.n4[j]) return;
    float4 v = ((const float4*)J.src[j])[i4];
    ushort4 h;
    h.x = f2bf(v.x); h.y = f2bf(v.y); h.z = f2bf(v.z); h.w = f2bf(v.w);
    ((ushort4*)J.hi[j])[i4] = h;
    if (J.lo[j]) {
        ushort4 l;
        l.x = f2bf(v.x - bf2f(h.x));
        l.y = f2bf(v.y - bf2f(h.y));
        l.z = f2bf(v.z - bf2f(h.z));
        l.w = f2bf(v.w - bf2f(h.w));
        ((ushort4*)J.lo[j])[i4] = l;
    }
}

// ---------------------------------------------------------------------------
// S = I + h*A + h^2/2*A2 + h^3/6*A3 + h^4/24*A4; emit hi/lo split (row-major only).
__global__ __launch_bounds__(256) void taylor_k(const float* __restrict__ A_,
                                                const float* __restrict__ A2,
                                                const float* __restrict__ A3,
                                                const float* __restrict__ A4,
                                                unsigned short* __restrict__ Shi,
                                                unsigned short* __restrict__ Slo,
                                                int D, float h) {
    int idx = blockIdx.x * 256 + threadIdx.x;
    if (idx >= D * D) return;
    int i = idx / D, j = idx % D;
    float c2 = 0.5f * h * h;
    float c3 = h * h * h * (1.0f / 6.0f);
    float c4 = h * h * h * h * (1.0f / 24.0f);
    float s = (i == j ? 1.0f : 0.0f) + h * A_[idx] + c2 * A2[idx] + c3 * A3[idx] + c4 * A4[idx];
    unsigned short hi = f2bf(s);
    Shi[idx] = hi;
    Slo[idx] = f2bf(s - bf2f(hi));
}

// ---------------------------------------------------------------------------
// 64x64-tile MFMA **NN** GEMM with split-bf16 inputs (fp32-class accuracy):
//   C[M,N] = A[M,K] @ B[K,N],  A given as Ahi+Alo [M,K], B as Bhi+Blo [K,N].
// BK=32, 256 threads = 4 waves (2x2, each 32x32 = 2x2 MFMAs of 16x16x32).
// 3 MFMAs per position (hi*hi + hi*lo + lo*hi). VGPR->LDS staging (no GLDS).
// Outputs by nullness: Cf32, Chi, Clo (all row-major [M,N]).
// Requires M%64==0, N%64==0, K%32==0.
__global__ __launch_bounds__(256) void gemm64nn(int M, int N, int K,
                                                const unsigned short* __restrict__ Ahi,
                                                const unsigned short* __restrict__ Alo,
                                                const unsigned short* __restrict__ Bhi,
                                                const unsigned short* __restrict__ Blo,
                                                float* __restrict__ Cf32,
                                                unsigned short* __restrict__ Chi,
                                                unsigned short* __restrict__ Clo) {
    __shared__ unsigned short As[64 * 32];   // [m][k]
    __shared__ unsigned short Al[64 * 32];
    __shared__ unsigned short Bs[32 * 64];   // [k][n]
    __shared__ unsigned short Bl[32 * 64];

    const int tid = threadIdx.x;
    const int lane = tid & 63;
    const int wave = tid >> 6;
    const int wr = wave >> 1, wc = wave & 1;
    const int row0 = blockIdx.y * 64;
    const int col0 = blockIdx.x * 64;

    // A staging: thread t covers A[row0 + (t>>2)][k0 + (t&3)*8 .. +8)
    const int am = tid >> 2;
    const int ak = (tid & 3) * 8;
    // B staging: thread t covers B[k0 + (t>>3)][col0 + (t&7)*8 .. +8)
    const int bk = tid >> 3;
    const int bn = (tid & 7) * 8;

    f32x4 acc[4] = {};  // [mt*2+nt]

    for (int k0 = 0; k0 < K; k0 += 32) {
        bf16x8 avh = *(const bf16x8*)(Ahi + (size_t)(row0 + am) * K + k0 + ak);
        bf16x8 avl = *(const bf16x8*)(Alo + (size_t)(row0 + am) * K + k0 + ak);
        bf16x8 bvh = *(const bf16x8*)(Bhi + (size_t)(k0 + bk) * N + col0 + bn);
        bf16x8 bvl = *(const bf16x8*)(Blo + (size_t)(k0 + bk) * N + col0 + bn);
        if (k0) __syncthreads();  // protect previous iteration's LDS reads
        *(bf16x8*)&As[am * 32 + ak] = avh;
        *(bf16x8*)&Al[am * 32 + ak] = avl;
        *(bf16x8*)&Bs[bk * 64 + bn] = bvh;
        *(bf16x8*)&Bl[bk * 64 + bn] = bvl;
        __syncthreads();  // publish

        const int kk = (lane >> 4) * 8;        // k-octet for this quad
        const int mrow = wr * 32 + (lane & 15);
        const int ncol = wc * 32 + (lane & 15);
        bf16x8 ah[2], al8[2], bh[2], bl8[2];
#pragma unroll
        for (int t = 0; t < 2; ++t) {
            ah[t] = *(const bf16x8*)&As[(mrow + t * 16) * 32 + kk];
            al8[t] = *(const bf16x8*)&Al[(mrow + t * 16) * 32 + kk];
            // B fragment: lane needs B[k=kk+j][n=ncol+t*16], gather 8 scalars
#pragma unroll
            for (int j = 0; j < 8; ++j) {
                bh[t][j] = (short)Bs[(kk + j) * 64 + ncol + t * 16];
                bl8[t][j] = (short)Bl[(kk + j) * 64 + ncol + t * 16];
            }
        }
#pragma unroll
        for (int mt = 0; mt < 2; ++mt)
#pragma unroll
            for (int nt = 0; nt < 2; ++nt) {
                acc[mt * 2 + nt] = __builtin_amdgcn_mfma_f32_16x16x32_bf16(
                    ah[mt], bh[nt], acc[mt * 2 + nt], 0, 0, 0);
                acc[mt * 2 + nt] = __builtin_amdgcn_mfma_f32_16x16x32_bf16(
                    ah[mt], bl8[nt], acc[mt * 2 + nt], 0, 0, 0);
                acc[mt * 2 + nt] = __builtin_amdgcn_mfma_f32_16x16x32_bf16(
                    al8[mt], bh[nt], acc[mt * 2 + nt], 0, 0, 0);
            }
    }

    // epilogue — C/D layout: col=lane&15, row=(lane>>4)*4+reg
#pragma unroll
    for (int mt = 0; mt < 2; ++mt) {
        const int grow = row0 + wr * 32 + mt * 16 + (lane >> 4) * 4;
#pragma unroll
        for (int nt = 0; nt < 2; ++nt) {
            const int gcol = col0 + wc * 32 + nt * 16 + (lane & 15);
#pragma unroll
            for (int i = 0; i < 4; ++i) {
                float x = acc[mt * 2 + nt][i];
                const size_t off = (size_t)(grow + i) * N + gcol;
                if (Cf32) Cf32[off] = x;
                unsigned short hh = f2bf(x);
                if (Chi) Chi[off] = hh;
                if (Clo) Clo[off] = f2bf(x - bf2f(hh));
            }
        }
    }
}

// ---------------------------------------------------------------------------
// Big bf16 MFMA GEMM (proven rounds 2-3): C[M,N] = A[M,K] @ B[N,K]^T (+bias)(relu)
// 128x128 tile, BK=32, 4 waves 2x2 (each 64x64). M%128==0, N%128==0, K%32==0.
template <int RELU, int BIAS, int OUT_BF16>
__global__ __launch_bounds__(256) void gemm_bf16(int M, int N, int K,
                                                 const unsigned short* __restrict__ A,
                                                 const unsigned short* __restrict__ B,
                                                 void* __restrict__ C,
                                                 const float* __restrict__ bias) {
    __shared__ unsigned short As[128 * 32];
    __shared__ unsigned short Bs[128 * 32];

    const int tid = threadIdx.x;
    const int lane = tid & 63;
    const int wave = tid >> 6;
    const int wr = wave >> 1, wc = wave & 1;
    const int row0 = blockIdx.y * 128;
    const int col0 = blockIdx.x * 128;

    const int srow = lane >> 2;
    const int schunk = (lane & 3) * 8;

    f32x4 acc[4][4] = {};

    for (int k0 = 0; k0 < K; k0 += 32) {
        const int r0 = wave * 32;
        GLDS16(A + (size_t)(row0 + r0 + srow) * K + k0 + schunk, &As[r0 * 32]);
        GLDS16(A + (size_t)(row0 + r0 + 16 + srow) * K + k0 + schunk, &As[(r0 + 16) * 32]);
        GLDS16(B + (size_t)(col0 + r0 + srow) * K + k0 + schunk, &Bs[r0 * 32]);
        GLDS16(B + (size_t)(col0 + r0 + 16 + srow) * K + k0 + schunk, &Bs[(r0 + 16) * 32]);
        __syncthreads();

        const int kk = (lane >> 4) * 8;
        const int mbase = wr * 64 + (lane & 15);
        const int nbase = wc * 64 + (lane & 15);
        bf16x8 af[4], bf[4];
#pragma unroll
        for (int t = 0; t < 4; ++t) {
            af[t] = *(const bf16x8*)&As[(mbase + t * 16) * 32 + kk];
            bf[t] = *(const bf16x8*)&Bs[(nbase + t * 16) * 32 + kk];
        }
#pragma unroll
        for (int mt = 0; mt < 4; ++mt)
#pragma unroll
            for (int nt = 0; nt < 4; ++nt)
                acc[mt][nt] = __builtin_amdgcn_mfma_f32_16x16x32_bf16(af[mt], bf[nt],
                                                                      acc[mt][nt], 0, 0, 0);
        __syncthreads();
    }

#pragma unroll
    for (int mt = 0; mt < 4; ++mt) {
        const int grow = row0 + wr * 64 + mt * 16 + (lane >> 4) * 4;
#pragma unroll
        for (int nt = 0; nt < 4; ++nt) {
            const int gcol = col0 + wc * 64 + nt * 16 + (lane & 15);
            const float bv = BIAS ? bias[gcol] : 0.0f;
#pragma unroll
            for (int i = 0; i < 4; ++i) {
                float v = acc[mt][nt][i] + bv;
                if (RELU) v = fmaxf(v, 0.0f);
                const size_t off = (size_t)(grow + i) * N + gcol;
                if (OUT_BF16)
                    ((unsigned short*)C)[off] = f2bf(v);
                else
                    ((float*)C)[off] = v;
            }
        }
    }
}

// ---------------------------------------------------------------------------
extern "C" void kernel_launch(void* const* d_in, const int* in_sizes, int n_in,
                              void* d_out, int out_size, void* d_ws, size_t ws_size,
                              hipStream_t stream) {
    const float* X  = (const float*)d_in[0];  // [B, Dx]
    const float* P  = (const float*)d_in[1];  // [Dz, Dx]
    const float* Am = (const float*)d_in[2];  // [Dz, Dz]
    const float* W1 = (const float*)d_in[3];  // [H, Dz]
    const float* b1 = (const float*)d_in[4];
    const float* W2 = (const float*)d_in[5];  // [H, H]
    const float* b2 = (const float*)d_in[6];
    const float* W3 = (const float*)d_in[7];  // [Dy, H]
    const float* b3 = (const float*)d_in[8];
    float* out = (float*)d_out;               // [B, Dy] fp32

    const float h = 1.0f / (float)NSTEPS;
    const size_t S = (size_t)DZ * DZ;  // 262144

    // ---- workspace carve-up (~58 MB; round 1 demonstrated >=76 MB available) ----
    char* p = (char*)d_ws;
    auto alloc_f = [&](size_t n) { float* r = (float*)p; p += n * 4; return r; };
    auto alloc_h = [&](size_t n) { unsigned short* r = (unsigned short*)p; p += ((n * 2 + 15) & ~15ull); return r; };
    unsigned short* Xb  = alloc_h((size_t)BDIM * DX);
    unsigned short* W2b = alloc_h((size_t)HD * HD);
    unsigned short* W3b = alloc_h((size_t)DY * HD);
    unsigned short* W1h = alloc_h((size_t)HD * DZ);
    unsigned short* W1l = alloc_h((size_t)HD * DZ);
    unsigned short* Ah  = alloc_h(S);
    unsigned short* Al  = alloc_h(S);
    unsigned short* Ph  = alloc_h(S);
    unsigned short* Pl  = alloc_h(S);
    float* M2f = alloc_f(S);
    float* M3f = alloc_f(S);
    float* M4f = alloc_f(S);
    unsigned short* M2h = alloc_h(S);
    unsigned short* M2l = alloc_h(S);
    unsigned short* Sh[2] = {alloc_h(S), alloc_h(S)};
    unsigned short* Sl[2] = {alloc_h(S), alloc_h(S)};
    unsigned short* Rh  = alloc_h(S);
    unsigned short* Rl  = alloc_h(S);
    unsigned short* C1b = alloc_h((size_t)HD * DZ);
    unsigned short* h1b = alloc_h((size_t)BDIM * HD);
    unsigned short* h2b = alloc_h((size_t)BDIM * HD);

    // ---- 1 launch: all input converts / splits ----
    CvtJobs J;
    J.src[0] = X;  J.hi[0] = Xb;  J.lo[0] = nullptr; J.n4[0] = BDIM * DX / 4;
    J.src[1] = W2; J.hi[1] = W2b; J.lo[1] = nullptr; J.n4[1] = HD * HD / 4;
    J.src[2] = W3; J.hi[2] = W3b; J.lo[2] = nullptr; J.n4[2] = DY * HD / 4;
    J.src[3] = W1; J.hi[3] = W1h; J.lo[3] = W1l;     J.n4[3] = HD * DZ / 4;
    J.src[4] = Am; J.hi[4] = Ah;  J.lo[4] = Al;      J.n4[4] = (int)(S / 4);
    J.src[5] = P;  J.hi[5] = Ph;  J.lo[5] = Pl;      J.n4[5] = (int)(S / 4);
    cvt_multi_k<<<dim3(HD * HD / 4 / 256, 6), 256, 0, stream>>>(J);

    dim3 g512(DZ / 64, DZ / 64);  // 8x8 = 64 blocks

    // M2 = A@A (f32 + split); M3 = M2@A (f32); M4 = M2@M2 (f32)  — all NN
    gemm64nn<<<g512, 256, 0, stream>>>(DZ, DZ, DZ, Ah, Al, Ah, Al, M2f, M2h, M2l);
    gemm64nn<<<g512, 256, 0, stream>>>(DZ, DZ, DZ, M2h, M2l, Ah, Al, M3f, nullptr, nullptr);
    gemm64nn<<<g512, 256, 0, stream>>>(DZ, DZ, DZ, M2h, M2l, M2h, M2l, M4f, nullptr, nullptr);
    // S0 = taylor4 (split)
    taylor_k<<<(int)(S + 255) / 256, 256, 0, stream>>>(Am, M2f, M3f, M4f, Sh[0], Sl[0], DZ, h);
    // Q = S^64 via 6 squarings (NN, split in/out)
    int cur = 0;
    for (int s = 0; s < 6; ++s) {
        gemm64nn<<<g512, 256, 0, stream>>>(DZ, DZ, DZ, Sh[cur], Sl[cur], Sh[cur], Sl[cur],
                                           nullptr, Sh[1 - cur], Sl[1 - cur]);
        cur ^= 1;
    }
    // R = Q @ P (NN, split out)   [Dz, Dx]
    gemm64nn<<<g512, 256, 0, stream>>>(DZ, DZ, DZ, Sh[cur], Sl[cur], Ph, Pl,
                                       nullptr, Rh, Rl);
    // C1 = W1 @ R (NN, hi out)    [H, Dx]  — NT-ready B operand for the h1 GEMM
    gemm64nn<<<dim3(DZ / 64, HD / 64), 256, 0, stream>>>(HD, DZ, DZ, W1h, W1l, Rh, Rl,
                                                         nullptr, C1b, nullptr);

    // h1 = relu(X @ C1^T + b1)   [B, H], K=Dx
    gemm_bf16<1, 1, 1><<<dim3(HD / 128, BDIM / 128), 256, 0, stream>>>(
        BDIM, HD, DX, Xb, C1b, h1b, b1);
    // h2 = relu(h1 @ W2^T + b2)  [B, H]
    gemm_bf16<1, 1, 1><<<dim3(HD / 128, BDIM / 128), 256, 0, stream>>>(
        BDIM, HD, HD, h1b, W2b, h2b, b2);
    // y = h2 @ W3^T + b3         [B, Dy] fp32 out (proven round-2 path)
    gemm_bf16<0, 1, 0><<<dim3(DY / 128, BDIM / 128), 256, 0, stream>>>(
        BDIM, DY, HD, h2b, W3b, out, b3);
}